// Round 1
// baseline (571.030 us; speedup 1.0000x reference)
//
#include <hip/hip_runtime.h>

typedef __attribute__((ext_vector_type(8))) short short8;
typedef __attribute__((ext_vector_type(4))) float floatx4;

__device__ __forceinline__ unsigned short bf16_rne(float f) {
  unsigned int u = __builtin_bit_cast(unsigned int, f);
  u += 0x7fffu + ((u >> 16) & 1u);
  return (unsigned short)(u >> 16);
}

// ---------------- kernel 1: global average pool: x (32,256,56,56) -> pooled (32,256) ----------------
__global__ __launch_bounds__(256) void pool_kernel(const float* __restrict__ x,
                                                   float* __restrict__ pooled) {
  const int bc = blockIdx.x;                      // b*256 + c, 0..8191
  const float* p = x + (size_t)bc * 3136;
  float s = 0.f;
  for (int i = threadIdx.x; i < 3136; i += 256) s += p[i];
  __shared__ float red[256];
  red[threadIdx.x] = s;
  __syncthreads();
  #pragma unroll
  for (int off = 128; off > 0; off >>= 1) {
    if (threadIdx.x < off) red[threadIdx.x] += red[threadIdx.x + off];
    __syncthreads();
  }
  if (threadIdx.x == 0) pooled[bc] = red[0] * (1.f / 3136.f);
}

// ---------------- kernel 2: att[b][k] = sigmoid(pooled[b] . att_w[k]) ----------------
__global__ void att_kernel(const float* __restrict__ pooled,
                           const float* __restrict__ att_w,
                           float* __restrict__ att) {
  const int t = threadIdx.x;                      // 128 threads: b = t>>2, k = t&3
  const int b = t >> 2, k = t & 3;
  float z = 0.f;
  for (int ci = 0; ci < 256; ++ci)
    z += pooled[b * 256 + ci] * att_w[k * 256 + ci];
  att[t] = 1.f / (1.f + expf(-z));
}

// ---------------- kernel 3: agg[b][co][rs*256+ci] = bf16( sum_e att[b][e]*w[e][co][ci][rs] ) ----------------
__global__ __launch_bounds__(256) void agg_kernel(const float* __restrict__ w,
                                                  const float* __restrict__ att,
                                                  unsigned short* __restrict__ agg) {
  const int tg = blockIdx.x * 256 + threadIdx.x;  // 0..73727 = co*288 + rs*32 + ci8
  const int ci8 = tg & 31;
  const int rs  = (tg >> 5) % 9;
  const int co  = tg / 288;
  const int ci0 = ci8 * 8;
  float we[4][8];
  #pragma unroll
  for (int e = 0; e < 4; ++e)
    #pragma unroll
    for (int j = 0; j < 8; ++j)
      we[e][j] = w[(size_t)((e * 256 + co) * 256 + ci0 + j) * 9 + rs];
  __shared__ float attl[128];
  if (threadIdx.x < 128) attl[threadIdx.x] = att[threadIdx.x];
  __syncthreads();
  for (int b = 0; b < 32; ++b) {
    const float a0 = attl[b * 4 + 0], a1 = attl[b * 4 + 1];
    const float a2 = attl[b * 4 + 2], a3 = attl[b * 4 + 3];
    short8 h;
    #pragma unroll
    for (int j = 0; j < 8; ++j) {
      float s = a0 * we[0][j] + a1 * we[1][j] + a2 * we[2][j] + a3 * we[3][j];
      h[j] = (short)bf16_rne(s);
    }
    *(short8*)(agg + (size_t)(b * 256 + co) * 2304 + rs * 256 + ci0) = h;
  }
}

// ---------------- kernel 4: implicit-GEMM conv, 128co x 128p tile, bf16 MFMA ----------------
// A = agg weights [co][k], B = shifted x patches [k][p], k = rs*256+ci, BK=32 (fixed rs per chunk)
__global__ __launch_bounds__(256) void conv_kernel(const float* __restrict__ x,
                                                   const unsigned short* __restrict__ aggw,
                                                   float* __restrict__ out) {
  __shared__ unsigned short Asm[128 * 40];  // co rows, pitch 40 ush (80B) -> bank-friendly
  __shared__ unsigned short Bsm[128 * 40];  // p rows,  pitch 40 ush

  const int t  = threadIdx.x;
  const int bx = blockIdx.x;
  const int p_t  = bx % 25;
  const int co_t = (bx / 25) & 1;
  const int b    = bx / 50;

  const float* xb = x + (size_t)b * (256 * 3136);
  const unsigned short* awb = aggw + (size_t)(b * 256 + co_t * 128) * 2304;

  // staging roles: thread -> (p row sp, k-octet pair ou/ou+2)
  const int sp = t & 127;
  const int ou = t >> 7;                    // 0/1
  const int p_flat = p_t * 128 + sp;
  const int oh = p_flat / 56;
  const int ow = p_flat - oh * 56;
  const bool prow_ok = (p_flat < 3136);

  // mfma roles
  const int lane = t & 63;
  const int wv = t >> 6;
  const int wm = wv >> 1;                   // co half
  const int wn = wv & 1;                    // p half
  const int m16 = lane & 15;
  const int q = lane >> 4;

  floatx4 acc[4][4];
  #pragma unroll
  for (int i = 0; i < 4; ++i)
    #pragma unroll
    for (int j = 0; j < 4; ++j)
      acc[i][j] = (floatx4){0.f, 0.f, 0.f, 0.f};

  const int arow0 = t >> 2;                 // A staging: row 0..63 (+64), chunk t&3
  const int ach   = t & 3;

  for (int rs = 0; rs < 9; ++rs) {
    const int r = rs / 3, s = rs - 3 * r;
    const int ih = oh + r - 1, iw = ow + s - 1;
    const bool valid = prow_ok && ((unsigned)ih < 56u) && ((unsigned)iw < 56u);
    const float* xsrc = xb + (ih * 56 + iw);      // deref'd only when valid
    const unsigned short* arows = awb + rs * 256;

    for (int kc = 0; kc < 8; ++kc) {
      // ---- stage A tile (128 x 32 bf16): 16B chunks, coalesced ----
      #pragma unroll
      for (int it = 0; it < 2; ++it) {
        const int row = arow0 + it * 64;
        const short8 av = *(const short8*)(arows + (size_t)row * 2304 + kc * 32 + ach * 8);
        *(short8*)(&Asm[row * 40 + ach * 8]) = av;
      }
      // ---- stage B tile: 8 ci-strided f32 loads per octet, cvt->bf16, one b128 write ----
      {
        float v0[8], v1[8];
        const int c0 = (kc * 32 + ou * 8) * 3136;
        const int c1 = (kc * 32 + (ou + 2) * 8) * 3136;
        if (valid) {
          #pragma unroll
          for (int j = 0; j < 8; ++j) v0[j] = xsrc[c0 + j * 3136];
          #pragma unroll
          for (int j = 0; j < 8; ++j) v1[j] = xsrc[c1 + j * 3136];
        } else {
          #pragma unroll
          for (int j = 0; j < 8; ++j) { v0[j] = 0.f; v1[j] = 0.f; }
        }
        short8 h0, h1;
        #pragma unroll
        for (int j = 0; j < 8; ++j) {
          h0[j] = (short)bf16_rne(v0[j]);
          h1[j] = (short)bf16_rne(v1[j]);
        }
        *(short8*)(&Bsm[sp * 40 + ou * 8]) = h0;
        *(short8*)(&Bsm[sp * 40 + (ou + 2) * 8]) = h1;
      }
      __syncthreads();

      short8 af[4], bf[4];
      #pragma unroll
      for (int i = 0; i < 4; ++i)
        af[i] = *(const short8*)(&Asm[(wm * 64 + i * 16 + m16) * 40 + q * 8]);
      #pragma unroll
      for (int i = 0; i < 4; ++i)
        bf[i] = *(const short8*)(&Bsm[(wn * 64 + i * 16 + m16) * 40 + q * 8]);
      #pragma unroll
      for (int i = 0; i < 4; ++i)
        #pragma unroll
        for (int j = 0; j < 4; ++j)
          acc[i][j] = __builtin_amdgcn_mfma_f32_16x16x32_bf16(af[i], bf[j], acc[i][j], 0, 0, 0);
      __syncthreads();
    }
  }

  // ---- epilogue: D col = lane&15 (p), row = q*4+reg (co) ----
  #pragma unroll
  for (int i = 0; i < 4; ++i) {
    const int co = co_t * 128 + wm * 64 + i * 16 + q * 4;
    float* orow = out + (size_t)(b * 256 + co) * 3136;
    #pragma unroll
    for (int j = 0; j < 4; ++j) {
      const int p0 = p_t * 128 + wn * 64 + j * 16 + m16;
      if (p0 < 3136) {
        #pragma unroll
        for (int rg = 0; rg < 4; ++rg)
          orow[(size_t)rg * 3136 + p0] = acc[i][j][rg];
      }
    }
  }
}

extern "C" void kernel_launch(void* const* d_in, const int* in_sizes, int n_in,
                              void* d_out, int out_size, void* d_ws, size_t ws_size,
                              hipStream_t stream) {
  const float* x      = (const float*)d_in[0];   // (32,256,56,56)
  const float* att_w  = (const float*)d_in[1];   // (4,256)
  const float* weight = (const float*)d_in[2];   // (4,256,256,3,3)
  float* out = (float*)d_out;                    // (32,256,56,56)

  char* ws = (char*)d_ws;
  float* pooled      = (float*)ws;               // 32 KB
  float* att         = (float*)(ws + 32768);     // 512 B
  unsigned short* agg = (unsigned short*)(ws + 65536); // 37,748,736 B bf16

  pool_kernel<<<8192, 256, 0, stream>>>(x, pooled);
  att_kernel<<<1, 128, 0, stream>>>(pooled, att_w, att);
  agg_kernel<<<288, 256, 0, stream>>>(weight, att, agg);
  conv_kernel<<<1600, 256, 0, stream>>>(x, agg, out);
}

// Round 2
// 403.887 us; speedup vs baseline: 1.4138x; 1.4138x over previous
//
#include <hip/hip_runtime.h>

typedef __attribute__((ext_vector_type(8))) short short8;
typedef __attribute__((ext_vector_type(4))) float floatx4;

__device__ __forceinline__ unsigned short bf16_rne(float f) {
  unsigned int u = __builtin_bit_cast(unsigned int, f);
  u += 0x7fffu + ((u >> 16) & 1u);
  return (unsigned short)(u >> 16);
}

__device__ __forceinline__ void glds16(const void* g, void* l) {
  __builtin_amdgcn_global_load_lds((const __attribute__((address_space(1))) void*)g,
                                   (__attribute__((address_space(3))) void*)l, 16, 0, 0);
}

// ---------------- zero pooled (32x256 floats) ----------------
__global__ __launch_bounds__(256) void zero_pooled_kernel(float* __restrict__ pooled) {
  pooled[blockIdx.x * 256 + threadIdx.x] = 0.f;
}

// ---------------- prep: x (32,256,56,56) f32 -> xpad[b][h+1][w+1][ci] bf16 (58x58 padded),
// fused global-sum into pooled[b][ci] ----------------
__global__ __launch_bounds__(256) void prep_kernel(const float* __restrict__ x,
                                                   unsigned short* __restrict__ xpad,
                                                   float* __restrict__ pooled) {
  // grid: 32 b x 4 cig(64 ci) x 49 spc(64 spatial)
  const int bid = blockIdx.x;
  const int b   = bid / 196;
  const int rem = bid - b * 196;
  const int cig = rem / 49;
  const int spc = rem - cig * 49;
  const int t  = threadIdx.x;
  const int cs = t >> 6;        // wave id 0..3
  const int sl = t & 63;        // lane
  const int sp0 = spc * 64;

  __shared__ float T[64][65];

  // phase 1: coalesced read (64 spatial per row), transpose into LDS, pool-reduce
  #pragma unroll
  for (int i = 0; i < 16; ++i) {
    const int cil = cs * 16 + i;
    float v = x[(size_t)((b * 256 + cig * 64 + cil)) * 3136 + sp0 + sl];
    T[cil][sl] = v;
    float s = v;
    #pragma unroll
    for (int o = 32; o > 0; o >>= 1) s += __shfl_xor(s, o, 64);
    if (sl == 0) atomicAdd(&pooled[b * 256 + cig * 64 + cil], s);
  }
  __syncthreads();

  // phase 2: write bf16, ci innermost (coalesced 128B per 64 lanes)
  const int g = t >> 6;
  unsigned short* xpb = xpad + (size_t)b * (58 * 58 * 256) + cig * 64 + sl;
  #pragma unroll
  for (int i = 0; i < 16; ++i) {
    const int spl = g * 16 + i;
    const int spg = sp0 + spl;
    const int h = spg / 56;
    const int w = spg - h * 56;
    xpb[(size_t)((h + 1) * 58 + (w + 1)) * 256] = bf16_rne(T[sl][spl]);
  }
}

// ---------------- zero the padding border of xpad ----------------
__global__ __launch_bounds__(256) void border_kernel(unsigned short* __restrict__ xpad) {
  const int b = blockIdx.x;
  const int quarter = blockIdx.y;          // 228 border positions = 4 x 57
  const int t = threadIdx.x;
  const short8 z = {0, 0, 0, 0, 0, 0, 0, 0};
  unsigned short* xb = xpad + (size_t)b * (58 * 58 * 256);
  for (int it = 0; it < 8; ++it) {
    const int j = it * 8 + (t >> 5);
    if (j >= 57) break;
    const int pi = quarter * 57 + j;
    int h2, w2;
    if (pi < 58)        { h2 = 0;  w2 = pi; }
    else if (pi < 116)  { h2 = 57; w2 = pi - 58; }
    else { const int k = pi - 116; h2 = 1 + (k >> 1); w2 = (k & 1) * 57; }
    *(short8*)(xb + (size_t)(h2 * 58 + w2) * 256 + (t & 31) * 8) = z;
  }
}

// ---------------- att[b][k] = sigmoid(mean . att_w[k]) (pooled holds SUM) ----------------
__global__ void att_kernel(const float* __restrict__ pooled,
                           const float* __restrict__ att_w,
                           float* __restrict__ att) {
  const int t = threadIdx.x;               // 128: b = t>>2, k = t&3
  const int b = t >> 2, k = t & 3;
  float z = 0.f;
  for (int ci = 0; ci < 256; ++ci)
    z += pooled[b * 256 + ci] * att_w[k * 256 + ci];
  z *= (1.f / 3136.f);
  att[t] = 1.f / (1.f + expf(-z));
}

// ---------------- agg[b][co][rs*256+ci] = bf16( sum_e att[b][e]*w[e][co][ci][rs] ) ----------------
__global__ __launch_bounds__(256) void agg_kernel(const float* __restrict__ w,
                                                  const float* __restrict__ att,
                                                  unsigned short* __restrict__ agg) {
  const int tg = blockIdx.x * 256 + threadIdx.x;  // co*288 + rs*32 + ci8
  const int ci8 = tg & 31;
  const int rs  = (tg >> 5) % 9;
  const int co  = tg / 288;
  const int ci0 = ci8 * 8;
  float we[4][8];
  #pragma unroll
  for (int e = 0; e < 4; ++e)
    #pragma unroll
    for (int j = 0; j < 8; ++j)
      we[e][j] = w[(size_t)((e * 256 + co) * 256 + ci0 + j) * 9 + rs];
  __shared__ float attl[128];
  if (threadIdx.x < 128) attl[threadIdx.x] = att[threadIdx.x];
  __syncthreads();
  for (int b = 0; b < 32; ++b) {
    const float a0 = attl[b * 4 + 0], a1 = attl[b * 4 + 1];
    const float a2 = attl[b * 4 + 2], a3 = attl[b * 4 + 3];
    short8 h;
    #pragma unroll
    for (int j = 0; j < 8; ++j) {
      float s = a0 * we[0][j] + a1 * we[1][j] + a2 * we[2][j] + a3 * we[3][j];
      h[j] = (short)bf16_rne(s);
    }
    *(short8*)(agg + (size_t)(b * 256 + co) * 2304 + rs * 256 + ci0) = h;
  }
}

// ---------------- conv: implicit GEMM, 128co x 128p, bf16 MFMA ----------------
// K-loop: ci-chunk(32) outer, rs inner; x tile (6x58x32ci) staged once per chunk via global_load_lds.
__global__ __launch_bounds__(256) void conv_kernel(const unsigned short* __restrict__ xpad,
                                                   const unsigned short* __restrict__ aggw,
                                                   float* __restrict__ out) {
  __shared__ unsigned short Bsm[348 * 32];   // [pos = row*58+col][ci 32] bf16, 22272 B
  __shared__ unsigned short Asm[128 * 32];   // [co][k 32] bf16, 8192 B

  const int t  = threadIdx.x;
  const int bx = blockIdx.x;
  const int p_t  = bx % 25;
  const int co_t = (bx / 25) & 1;
  const int b    = bx / 50;
  const int p0   = p_t * 128;
  const int oh_min = p0 / 56;

  const unsigned short* xb  = xpad + (size_t)b * (58 * 58 * 256);
  const unsigned short* awb = aggw + (size_t)(b * 256 + co_t * 128) * 2304;

  // mfma roles
  const int lane = t & 63;
  const int wv = t >> 6;
  const int wm = wv >> 1;                   // co half
  const int wn = wv & 1;                    // p half
  const int m16 = lane & 15;
  const int q = lane >> 4;

  // fragment base offsets (ush units)
  int aoff[4], boff[4];
  #pragma unroll
  for (int i = 0; i < 4; ++i)
    aoff[i] = (wm * 64 + i * 16 + m16) * 32 + q * 8;
  #pragma unroll
  for (int j = 0; j < 4; ++j) {
    const int pf = p0 + wn * 64 + j * 16 + m16;
    const int oh = pf / 56;
    const int ow = pf - oh * 56;
    boff[j] = ((oh - oh_min) * 58 + ow) * 32 + q * 8;
  }

  floatx4 acc[4][4];
  #pragma unroll
  for (int i = 0; i < 4; ++i)
    #pragma unroll
    for (int j = 0; j < 4; ++j)
      acc[i][j] = (floatx4){0.f, 0.f, 0.f, 0.f};

  for (int kc = 0; kc < 8; ++kc) {
    // ---- stage B x-tile: 348 pos x 32 ci, 1392 16B chunks via global_load_lds ----
    {
      const int kci = kc * 32;
      #pragma unroll
      for (int i = 0; i < 6; ++i) {
        const int c = i * 256 + t;
        if (c < 1392) {
          const int pos = c >> 2, sub = c & 3;
          const int prow = pos / 58;
          const int pcol = pos - prow * 58;
          int ih2 = oh_min + prow; if (ih2 > 57) ih2 = 57;   // clamp (dup rows unused)
          glds16(xb + ((size_t)(ih2 * 58 + pcol) * 256 + kci + sub * 8),
                 (void*)(Bsm + c * 8));
        }
      }
    }
    #pragma unroll
    for (int r = 0; r < 3; ++r) {
      #pragma unroll
      for (int s = 0; s < 3; ++s) {
        const int rs = r * 3 + s;
        // ---- stage A tile: 128 co x 32 k, 512 chunks ----
        #pragma unroll
        for (int i = 0; i < 2; ++i) {
          const int c = i * 256 + t;
          const int co = c >> 2, sub = c & 3;
          glds16(awb + (size_t)co * 2304 + rs * 256 + kc * 32 + sub * 8,
                 (void*)(Asm + c * 8));
        }
        __syncthreads();   // drains glds (vmcnt) + barrier

        const int d = (r * 58 + s) * 32;
        short8 af[4], bf[4];
        #pragma unroll
        for (int i = 0; i < 4; ++i)
          af[i] = *(const short8*)(Asm + aoff[i]);
        #pragma unroll
        for (int j = 0; j < 4; ++j)
          bf[j] = *(const short8*)(Bsm + boff[j] + d);
        #pragma unroll
        for (int i = 0; i < 4; ++i)
          #pragma unroll
          for (int j = 0; j < 4; ++j)
            acc[i][j] = __builtin_amdgcn_mfma_f32_16x16x32_bf16(af[i], bf[j], acc[i][j], 0, 0, 0);
        __syncthreads();   // protect Asm/Bsm overwrite
      }
    }
  }

  // ---- epilogue: D col = lane&15 (p), row = q*4+reg (co) ----
  #pragma unroll
  for (int i = 0; i < 4; ++i) {
    const int co = co_t * 128 + wm * 64 + i * 16 + q * 4;
    float* orow = out + (size_t)(b * 256 + co) * 3136;
    #pragma unroll
    for (int j = 0; j < 4; ++j) {
      const int pp = p0 + wn * 64 + j * 16 + m16;
      if (pp < 3136) {
        #pragma unroll
        for (int rg = 0; rg < 4; ++rg)
          orow[(size_t)rg * 3136 + pp] = acc[i][j][rg];
      }
    }
  }
}

extern "C" void kernel_launch(void* const* d_in, const int* in_sizes, int n_in,
                              void* d_out, int out_size, void* d_ws, size_t ws_size,
                              hipStream_t stream) {
  const float* x      = (const float*)d_in[0];   // (32,256,56,56)
  const float* att_w  = (const float*)d_in[1];   // (4,256)
  const float* weight = (const float*)d_in[2];   // (4,256,256,3,3)
  float* out = (float*)d_out;                    // (32,256,56,56)

  char* ws = (char*)d_ws;
  float* pooled       = (float*)ws;                           // 32 KB (sums)
  float* att          = (float*)(ws + 32768);                 // 512 B
  unsigned short* agg  = (unsigned short*)(ws + 65536);       // 37,748,736 B
  unsigned short* xpad = (unsigned short*)(ws + 65536 + 37748736); // 55,115,776 B

  zero_pooled_kernel<<<32, 256, 0, stream>>>(pooled);
  prep_kernel<<<6272, 256, 0, stream>>>(x, xpad, pooled);
  border_kernel<<<dim3(32, 4), 256, 0, stream>>>(xpad);
  att_kernel<<<1, 128, 0, stream>>>(pooled, att_w, att);
  agg_kernel<<<288, 256, 0, stream>>>(weight, att, agg);
  conv_kernel<<<1600, 256, 0, stream>>>(xpad, agg, out);
}